// Round 4
// baseline (377.578 us; speedup 1.0000x reference)
//
#include <hip/hip_runtime.h>
#include <stdint.h>

// ---------------------------------------------------------------------------
// CrossMultiheadDiffAttn on MI355X (gfx950)
// B=2, T=S=2048, EMBED=1024, HEADS=16; 2H=32 qk-heads of D=32, 16 v-heads of 64.
//
// Round 4: attention occupancy fix. 8-wave blocks with KV-split-2 (waves 0-3
// take s<1024, waves 4-7 take s>=1024), online-softmax partials merged via a
// two-phase LDS exchange. Single-buffered K/V regs + __launch_bounds__(512,4)
// to keep VGPR<=128 (4 waves/SIMD). XCD swizzle + s_setprio on MFMA clusters.
// ---------------------------------------------------------------------------

#define LAMBDA_INIT_F 0.7836057665316245f
#define OUT_SCALE_F   0.2163942334683755f   /* 1 - LAMBDA_INIT */
#define QK_SCALE_F    0.17677669529663687f  /* 32^-0.5 */
#define LOG2E_F       1.4426950408889634f

typedef _Float16 f16x8 __attribute__((ext_vector_type(8)));
typedef _Float16 f16x4 __attribute__((ext_vector_type(4)));
typedef _Float16 f16x2 __attribute__((ext_vector_type(2)));
typedef __fp16   h16x2 __attribute__((ext_vector_type(2)));
typedef float    f32x4 __attribute__((ext_vector_type(4)));
typedef float    f32x16 __attribute__((ext_vector_type(16)));

__device__ inline void gl_lds16(const void* g, void* l) {
  __builtin_amdgcn_global_load_lds(
      (const __attribute__((address_space(1))) void*)g,
      (__attribute__((address_space(3))) void*)l, 16, 0, 0);
}

__device__ inline f16x2 shx32(f16x2 v) {
  int i = __builtin_bit_cast(int, v);
  i = __shfl_xor(i, 32, 64);
  return __builtin_bit_cast(f16x2, i);
}

__device__ inline f16x2 cvtpk(float a, float b) {
  h16x2 r = __builtin_amdgcn_cvt_pkrtz(a, b);
  return __builtin_bit_cast(f16x2, r);
}

// --------------------------- f32 -> f16 convert ----------------------------
__global__ __launch_bounds__(256) void cvt_kernel(const float* __restrict__ x,
                                                  _Float16* __restrict__ y) {
  int i = (blockIdx.x * 256 + threadIdx.x) * 4;
  float4 v = *(const float4*)(x + i);
  f16x4 o;
  o[0] = (_Float16)v.x; o[1] = (_Float16)v.y;
  o[2] = (_Float16)v.z; o[3] = (_Float16)v.w;
  *(f16x4*)(y + i) = o;
}

// ---------------- W [K,N] f32 -> W^T [N,K] f16 (with scale) ----------------
__global__ __launch_bounds__(256) void wtrans_kernel(const float* __restrict__ W,
                                                     _Float16* __restrict__ Wt,
                                                     float scale) {
  __shared__ _Float16 t[64][65];
  const int tid = threadIdx.x;
  const int nb = blockIdx.x * 64, kb = blockIdx.y * 64;
#pragma unroll
  for (int p = 0; p < 16; ++p) {
    int i = p * 256 + tid;
    int r = i >> 6, c = i & 63;
    t[c][r] = (_Float16)(W[(size_t)(kb + r) * 1024 + nb + c] * scale);
  }
  __syncthreads();
#pragma unroll
  for (int p = 0; p < 16; ++p) {
    int i = p * 256 + tid;
    int r = i >> 6, c = i & 63;
    Wt[(size_t)(nb + r) * 1024 + kb + c] = t[r][c];
  }
}

// ------------------------------ lambda_full --------------------------------
__global__ void lambda_kernel(const float* __restrict__ lq1, const float* __restrict__ lk1,
                              const float* __restrict__ lq2, const float* __restrict__ lk2,
                              float* __restrict__ out) {
  int l = threadIdx.x;
  float a = (l < 32) ? lq1[l] * lk1[l] : 0.f;
  float b = (l < 32) ? lq2[l] * lk2[l] : 0.f;
#pragma unroll
  for (int m = 1; m < 64; m <<= 1) {
    a += __shfl_xor(a, m, 64);
    b += __shfl_xor(b, m, 64);
  }
  if (l == 0) out[0] = expf(a) - expf(b) + LAMBDA_INIT_F;
}

// --------------------- 128x128 f16 GEMM:  C = A @ Bt^T ---------------------
__global__ __launch_bounds__(256) void gemm128(const _Float16* __restrict__ A,
                                               const _Float16* __restrict__ Bt,
                                               _Float16* __restrict__ Cf16,
                                               float* __restrict__ Cf32,
                                               int M, int N, int K) {
  __shared__ alignas(16) _Float16 As[128 * 32];
  __shared__ alignas(16) _Float16 Bs[128 * 32];
  const int tid = threadIdx.x;
  const int lane = tid & 63, wid = tid >> 6;
  const int g = lane >> 4, ln = lane & 15;
  const int wm = wid >> 1, wn = wid & 1;
  const int bm = blockIdx.y * 128;
  const int bn = blockIdx.x * 128;

  f32x4 acc[4][4];
#pragma unroll
  for (int i = 0; i < 4; ++i)
#pragma unroll
    for (int j = 0; j < 4; ++j) acc[i][j] = (f32x4){0.f, 0.f, 0.f, 0.f};

  const int r0 = tid >> 2;
  const int c0 = (tid & 3) * 8;

  for (int kt = 0; kt < K; kt += 32) {
    __syncthreads();
#pragma unroll
    for (int l = 0; l < 2; ++l) {
      const _Float16* ga = A + (size_t)(bm + l * 64 + r0) * K + kt + c0;
      const _Float16* gb = Bt + (size_t)(bn + l * 64 + r0) * K + kt + c0;
      gl_lds16(ga, (void*)(As + l * 2048 + wid * 512));
      gl_lds16(gb, (void*)(Bs + l * 2048 + wid * 512));
    }
    __syncthreads();
    f16x8 af[4], bf[4];
#pragma unroll
    for (int i = 0; i < 4; ++i) {
      af[i] = *(const f16x8*)(As + (wm * 64 + i * 16 + ln) * 32 + g * 8);
      bf[i] = *(const f16x8*)(Bs + (wn * 64 + i * 16 + ln) * 32 + g * 8);
    }
#pragma unroll
    for (int i = 0; i < 4; ++i)
#pragma unroll
      for (int j = 0; j < 4; ++j)
        acc[i][j] = __builtin_amdgcn_mfma_f32_16x16x32_f16(af[i], bf[j], acc[i][j], 0, 0, 0);
  }

#pragma unroll
  for (int i = 0; i < 4; ++i) {
#pragma unroll
    for (int j = 0; j < 4; ++j) {
      int grow = bm + wm * 64 + i * 16 + g * 4;
      int gcol = bn + wn * 64 + j * 16 + ln;
#pragma unroll
      for (int r = 0; r < 4; ++r) {
        if (Cf32) Cf32[(size_t)(grow + r) * N + gcol] = acc[i][j][r];
        else      Cf16[(size_t)(grow + r) * N + gcol] = (_Float16)acc[i][j][r];
      }
    }
  }
}

// ------------------- register-resident differential attention --------------
// grid = 512 blocks (b,h,qtile of 128), 8 waves: (wid&3)=q-subtile,
// (wid>>2)=s-half. Per-lane softmax state (col=q layout from swapped MFMA).
// Partials merged via 2-phase LDS exchange at the end.
__global__ __launch_bounds__(512, 4) void diffattn(const _Float16* __restrict__ qb,
                                                   const _Float16* __restrict__ kb,
                                                   const _Float16* __restrict__ vT,
                                                   const float* __restrict__ lam_p,
                                                   const float* __restrict__ subw,
                                                   _Float16* __restrict__ attn16) {
  __shared__ float mrg[4][64][35];   // [upper-wave][lane][O(32), m, l] per comp

  const int tid = threadIdx.x;
  const int lane = tid & 63, wid = tid >> 6;
  const int q32 = lane & 31;
  const int hl = lane >> 5;
  const int wq = wid & 3;       // q-subtile within the 128-row tile
  const int sw = wid >> 2;      // s-half
  const int bid = blockIdx.x;
  const int wg = ((bid & 7) << 6) | (bid >> 3);   // XCD-aware swizzle (512=8*64)
  const int qt = wg & 15;
  const int h = (wg >> 4) & 15;
  const int b = wg >> 8;
  const int trow = qt * 128 + wq * 32 + q32;
  const float lam = lam_p[0];

  // Q B-fragments: lane holds Q[q=lane&31][d = 16*kt + 8*hl + i]
  const _Float16* qp = qb + ((size_t)b * 2048 + trow) * 1024 + 2 * h * 32 + hl * 8;
  f16x8 qf1_0 = *(const f16x8*)(qp);
  f16x8 qf1_1 = *(const f16x8*)(qp + 16);
  f16x8 qf2_0 = *(const f16x8*)(qp + 32);
  f16x8 qf2_1 = *(const f16x8*)(qp + 48);

  const _Float16* kbase = kb + (size_t)b * 2048 * 1024 + 2 * h * 32 + hl * 8;
  const _Float16* vbase = vT + ((size_t)(h * 64 + q32)) * 4096 + b * 2048 + hl * 8;

  f32x16 O1[2] = {}, O2[2] = {};
  float m1 = -1e30f, m2 = -1e30f, l1 = 0.f, l2 = 0.f;
  const f32x16 zf = {};

  auto LOADT = [&](f16x8* K4, f16x8* V4, int s0) {
    const _Float16* kp = kbase + (size_t)(s0 + q32) * 1024;
    K4[0] = *(const f16x8*)(kp);
    K4[1] = *(const f16x8*)(kp + 16);
    K4[2] = *(const f16x8*)(kp + 32);
    K4[3] = *(const f16x8*)(kp + 48);
    const _Float16* vp = vbase + s0;
    V4[0] = *(const f16x8*)(vp);
    V4[1] = *(const f16x8*)(vp + 16);
    V4[2] = *(const f16x8*)(vp + 32 * 4096);
    V4[3] = *(const f16x8*)(vp + 32 * 4096 + 16);
  };

  auto SOFTPACK = [&](const f32x16& st, float m, float& lsum, f16x8& pb0, f16x8& pb1) {
    float p[16];
    float rs = 0.f;
#pragma unroll
    for (int i = 0; i < 16; ++i) {
      p[i] = __builtin_amdgcn_exp2f(st[i] - m);
      rs += p[i];
    }
    lsum += rs + __shfl_xor(rs, 32, 64);
    f16x2 r[8], xr[8];
#pragma unroll
    for (int k = 0; k < 8; ++k) r[k] = cvtpk(p[2 * k], p[2 * k + 1]);
#pragma unroll
    for (int k = 0; k < 8; ++k) xr[k] = shx32(r[k]);
    union { f16x8 v; f16x2 h2[4]; } u0, u1;
    u0.h2[0] = hl ? xr[2] : r[0];
    u0.h2[1] = hl ? xr[3] : r[1];
    u0.h2[2] = hl ? r[2]  : xr[0];
    u0.h2[3] = hl ? r[3]  : xr[1];
    u1.h2[0] = hl ? xr[6] : r[4];
    u1.h2[1] = hl ? xr[7] : r[5];
    u1.h2[2] = hl ? r[6]  : xr[4];
    u1.h2[3] = hl ? r[7]  : xr[5];
    pb0 = u0.v; pb1 = u1.v;
  };

  auto PROC = [&](const f16x8* K4, const f16x8* V4) {
    __builtin_amdgcn_s_setprio(1);
    f32x16 st1 = __builtin_amdgcn_mfma_f32_32x32x16_f16(K4[0], qf1_0, zf, 0, 0, 0);
    f32x16 st2 = __builtin_amdgcn_mfma_f32_32x32x16_f16(K4[2], qf2_0, zf, 0, 0, 0);
    st1 = __builtin_amdgcn_mfma_f32_32x32x16_f16(K4[1], qf1_1, st1, 0, 0, 0);
    st2 = __builtin_amdgcn_mfma_f32_32x32x16_f16(K4[3], qf2_1, st2, 0, 0, 0);
    __builtin_amdgcn_s_setprio(0);

    float tm1 = st1[0], tm2 = st2[0];
#pragma unroll
    for (int i = 1; i < 16; ++i) {
      tm1 = fmaxf(tm1, st1[i]);
      tm2 = fmaxf(tm2, st2[i]);
    }
    tm1 = fmaxf(tm1, __shfl_xor(tm1, 32, 64));
    tm2 = fmaxf(tm2, __shfl_xor(tm2, 32, 64));

    // defer-max (T13): only rescale when a tile max exceeds running max + THR
    if (!__all(fmaxf(tm1 - m1, tm2 - m2) <= 11.5f)) {
      float mn1 = fmaxf(m1, tm1), mn2 = fmaxf(m2, tm2);
      float c1 = __builtin_amdgcn_exp2f(m1 - mn1);
      float c2 = __builtin_amdgcn_exp2f(m2 - mn2);
      m1 = mn1; m2 = mn2; l1 *= c1; l2 *= c2;
#pragma unroll
      for (int i = 0; i < 16; ++i) {
        O1[0][i] *= c1; O1[1][i] *= c1;
        O2[0][i] *= c2; O2[1][i] *= c2;
      }
    }

    f16x8 p1b0, p1b1, p2b0, p2b1;
    SOFTPACK(st1, m1, l1, p1b0, p1b1);
    SOFTPACK(st2, m2, l2, p2b0, p2b1);

    __builtin_amdgcn_s_setprio(1);
    O1[0] = __builtin_amdgcn_mfma_f32_32x32x16_f16(V4[0], p1b0, O1[0], 0, 0, 0);
    O1[0] = __builtin_amdgcn_mfma_f32_32x32x16_f16(V4[1], p1b1, O1[0], 0, 0, 0);
    O1[1] = __builtin_amdgcn_mfma_f32_32x32x16_f16(V4[2], p1b0, O1[1], 0, 0, 0);
    O1[1] = __builtin_amdgcn_mfma_f32_32x32x16_f16(V4[3], p1b1, O1[1], 0, 0, 0);
    O2[0] = __builtin_amdgcn_mfma_f32_32x32x16_f16(V4[0], p2b0, O2[0], 0, 0, 0);
    O2[0] = __builtin_amdgcn_mfma_f32_32x32x16_f16(V4[1], p2b1, O2[0], 0, 0, 0);
    O2[1] = __builtin_amdgcn_mfma_f32_32x32x16_f16(V4[2], p2b0, O2[1], 0, 0, 0);
    O2[1] = __builtin_amdgcn_mfma_f32_32x32x16_f16(V4[3], p2b1, O2[1], 0, 0, 0);
    __builtin_amdgcn_s_setprio(0);
  };

  f16x8 K4[4], V4[4];
  const int sbase = sw * 1024;
  for (int s0 = 0; s0 < 1024; s0 += 32) {
    LOADT(K4, V4, sbase + s0);
    PROC(K4, V4);
  }

  // ---- merge the two s-halves (2-phase LDS exchange, comp1 then comp2) ----
  // phase 1: component 1
  if (wid >= 4) {
    float* d = &mrg[wid - 4][lane][0];
#pragma unroll
    for (int t = 0; t < 2; ++t)
#pragma unroll
      for (int i = 0; i < 16; ++i) d[t * 16 + i] = O1[t][i];
    d[32] = m1; d[33] = l1;
  }
  __syncthreads();
  if (wid < 4) {
    const float* d = &mrg[wid][lane][0];
    float mo = d[32], lo = d[33];
    float mn = fmaxf(m1, mo);
    float ca = __builtin_amdgcn_exp2f(m1 - mn);
    float cb = __builtin_amdgcn_exp2f(mo - mn);
    m1 = mn; l1 = l1 * ca + lo * cb;
#pragma unroll
    for (int t = 0; t < 2; ++t)
#pragma unroll
      for (int i = 0; i < 16; ++i) O1[t][i] = O1[t][i] * ca + d[t * 16 + i] * cb;
  }
  __syncthreads();
  // phase 2: component 2
  if (wid >= 4) {
    float* d = &mrg[wid - 4][lane][0];
#pragma unroll
    for (int t = 0; t < 2; ++t)
#pragma unroll
      for (int i = 0; i < 16; ++i) d[t * 16 + i] = O2[t][i];
    d[32] = m2; d[33] = l2;
  }
  __syncthreads();
  if (wid >= 4) return;
  {
    const float* d = &mrg[wid][lane][0];
    float mo = d[32], lo = d[33];
    float mn = fmaxf(m2, mo);
    float ca = __builtin_amdgcn_exp2f(m2 - mn);
    float cb = __builtin_amdgcn_exp2f(mo - mn);
    m2 = mn; l2 = l2 * ca + lo * cb;
#pragma unroll
    for (int t = 0; t < 2; ++t)
#pragma unroll
      for (int i = 0; i < 16; ++i) O2[t][i] = O2[t][i] * ca + d[t * 16 + i] * cb;
  }

  // epilogue: diff, RMSNorm over 64 dims (local 32 + partner via 1 shuffle)
  float rl1 = 1.f / l1;
  float rl2 = lam / l2;
  float x[2][16];
  float ssq = 0.f;
#pragma unroll
  for (int et = 0; et < 2; ++et)
#pragma unroll
    for (int i = 0; i < 16; ++i) {
      float v = O1[et][i] * rl1 - O2[et][i] * rl2;
      x[et][i] = v;
      ssq += v * v;
    }
  ssq += __shfl_xor(ssq, 32, 64);
  float rms = rsqrtf(ssq * (1.f / 64.f) + 1e-5f) * OUT_SCALE_F;

  _Float16* orow = attn16 + ((size_t)b * 2048 + trow) * 1024 + h * 64;
#pragma unroll
  for (int et = 0; et < 2; ++et)
#pragma unroll
    for (int grp = 0; grp < 4; ++grp) {
      int e0 = et * 32 + grp * 8 + 4 * hl;
      float4 w = *(const float4*)(subw + e0);
      f16x4 o;
      o[0] = (_Float16)(x[et][grp * 4 + 0] * rms * w.x);
      o[1] = (_Float16)(x[et][grp * 4 + 1] * rms * w.y);
      o[2] = (_Float16)(x[et][grp * 4 + 2] * rms * w.z);
      o[3] = (_Float16)(x[et][grp * 4 + 3] * rms * w.w);
      *(f16x4*)(orow + e0) = o;
    }
}

// ---------------------------------------------------------------------------
extern "C" void kernel_launch(void* const* d_in, const int* in_sizes, int n_in,
                              void* d_out, int out_size, void* d_ws, size_t ws_size,
                              hipStream_t stream) {
  const float* query_x = (const float*)d_in[0];
  const float* kv_x    = (const float*)d_in[1];
  const float* Wq      = (const float*)d_in[2];
  const float* Wk      = (const float*)d_in[3];
  const float* Wv      = (const float*)d_in[4];
  const float* Wo      = (const float*)d_in[5];
  const float* lq1     = (const float*)d_in[6];
  const float* lk1     = (const float*)d_in[7];
  const float* lq2     = (const float*)d_in[8];
  const float* lk2     = (const float*)d_in[9];
  const float* subw    = (const float*)d_in[10];
  float* out = (float*)d_out;

  const size_t NX = (size_t)4096 * 1024;
  const size_t NW = (size_t)1024 * 1024;
  _Float16* xq  = (_Float16*)d_ws;
  _Float16* xkv = xq  + NX;
  _Float16* WqT = xkv + NX;
  _Float16* WkT = WqT + NW;
  _Float16* WvT = WkT + NW;
  _Float16* WoT = WvT + NW;
  _Float16* qb  = WoT + NW;
  _Float16* kbf = qb  + NX;
  _Float16* vTb = kbf + NX;   // V^T: [1024 rows = h*64+e][4096 cols = b*2048+s]
  _Float16* a16 = vTb + NX;
  float* lamv   = (float*)(a16 + NX);

  cvt_kernel<<<4096, 256, 0, stream>>>(query_x, xq);
  cvt_kernel<<<4096, 256, 0, stream>>>(kv_x, xkv);

  dim3 tg(16, 16);
  // Wq also folds log2e so attention scores are directly in exp2 domain
  wtrans_kernel<<<tg, 256, 0, stream>>>(Wq, WqT, QK_SCALE_F * LOG2E_F);
  wtrans_kernel<<<tg, 256, 0, stream>>>(Wk, WkT, 1.0f);
  wtrans_kernel<<<tg, 256, 0, stream>>>(Wv, WvT, 1.0f);
  wtrans_kernel<<<tg, 256, 0, stream>>>(Wo, WoT, 1.0f);
  lambda_kernel<<<1, 64, 0, stream>>>(lq1, lk1, lq2, lk2, lamv);

  dim3 gg(8, 32);   // (N/128, M/128) for 4096x1024
  gemm128<<<gg, 256, 0, stream>>>(xq,  WqT, qb,  nullptr, 4096, 1024, 1024);
  gemm128<<<gg, 256, 0, stream>>>(xkv, WkT, kbf, nullptr, 4096, 1024, 1024);
  // V^T directly: C[n][m] = sum_k WvT[n][k]*xkv[m][k] = V[m][n]
  dim3 gv(32, 8);   // (N/128=4096/128, M/128=1024/128)
  gemm128<<<gv, 256, 0, stream>>>(WvT, xkv, vTb, nullptr, 1024, 4096, 1024);

  diffattn<<<512, 512, 0, stream>>>(qb, kbf, vTb, lamv, subw, a16);

  gemm128<<<gg, 256, 0, stream>>>(a16, WoT, nullptr, out, 4096, 1024, 1024);
}

// Round 5
// 311.538 us; speedup vs baseline: 1.2120x; 1.2120x over previous
//
#include <hip/hip_runtime.h>
#include <stdint.h>

// ---------------------------------------------------------------------------
// CrossMultiheadDiffAttn on MI355X (gfx950)
// B=2, T=S=2048, EMBED=1024, HEADS=16; 2H=32 qk-heads of D=32, 16 v-heads of 64.
//
// Round 5: component-split attention. Each wave owns ONE diff-softmax
// component (comp = wid>>1) -> per-wave state halves (O=32 VGPR), fits
// 128 VGPR at 4 waves/SIMD with no spill. Block = 2 q-subtiles x 2 comps,
// grid = 1024 blocks (all co-resident). Comp-1 wave ships normalized O2/l2
// via LDS; comp-0 wave does diff + RMSNorm + store.
// ---------------------------------------------------------------------------

#define LAMBDA_INIT_F 0.7836057665316245f
#define OUT_SCALE_F   0.2163942334683755f   /* 1 - LAMBDA_INIT */
#define QK_SCALE_F    0.17677669529663687f  /* 32^-0.5 */
#define LOG2E_F       1.4426950408889634f

typedef _Float16 f16x8 __attribute__((ext_vector_type(8)));
typedef _Float16 f16x4 __attribute__((ext_vector_type(4)));
typedef _Float16 f16x2 __attribute__((ext_vector_type(2)));
typedef __fp16   h16x2 __attribute__((ext_vector_type(2)));
typedef float    f32x4 __attribute__((ext_vector_type(4)));
typedef float    f32x16 __attribute__((ext_vector_type(16)));

__device__ inline void gl_lds16(const void* g, void* l) {
  __builtin_amdgcn_global_load_lds(
      (const __attribute__((address_space(1))) void*)g,
      (__attribute__((address_space(3))) void*)l, 16, 0, 0);
}

__device__ inline f16x2 shx32(f16x2 v) {
  int i = __builtin_bit_cast(int, v);
  i = __shfl_xor(i, 32, 64);
  return __builtin_bit_cast(f16x2, i);
}

__device__ inline f16x2 cvtpk(float a, float b) {
  h16x2 r = __builtin_amdgcn_cvt_pkrtz(a, b);
  return __builtin_bit_cast(f16x2, r);
}

// --------------------------- f32 -> f16 convert ----------------------------
__global__ __launch_bounds__(256) void cvt_kernel(const float* __restrict__ x,
                                                  _Float16* __restrict__ y) {
  int i = (blockIdx.x * 256 + threadIdx.x) * 4;
  float4 v = *(const float4*)(x + i);
  f16x4 o;
  o[0] = (_Float16)v.x; o[1] = (_Float16)v.y;
  o[2] = (_Float16)v.z; o[3] = (_Float16)v.w;
  *(f16x4*)(y + i) = o;
}

// ---------------- W [K,N] f32 -> W^T [N,K] f16 (with scale) ----------------
__global__ __launch_bounds__(256) void wtrans_kernel(const float* __restrict__ W,
                                                     _Float16* __restrict__ Wt,
                                                     float scale) {
  __shared__ _Float16 t[64][65];
  const int tid = threadIdx.x;
  const int nb = blockIdx.x * 64, kb = blockIdx.y * 64;
#pragma unroll
  for (int p = 0; p < 16; ++p) {
    int i = p * 256 + tid;
    int r = i >> 6, c = i & 63;
    t[c][r] = (_Float16)(W[(size_t)(kb + r) * 1024 + nb + c] * scale);
  }
  __syncthreads();
#pragma unroll
  for (int p = 0; p < 16; ++p) {
    int i = p * 256 + tid;
    int r = i >> 6, c = i & 63;
    Wt[(size_t)(nb + r) * 1024 + kb + c] = t[r][c];
  }
}

// ------------------------------ lambda_full --------------------------------
__global__ void lambda_kernel(const float* __restrict__ lq1, const float* __restrict__ lk1,
                              const float* __restrict__ lq2, const float* __restrict__ lk2,
                              float* __restrict__ out) {
  int l = threadIdx.x;
  float a = (l < 32) ? lq1[l] * lk1[l] : 0.f;
  float b = (l < 32) ? lq2[l] * lk2[l] : 0.f;
#pragma unroll
  for (int m = 1; m < 64; m <<= 1) {
    a += __shfl_xor(a, m, 64);
    b += __shfl_xor(b, m, 64);
  }
  if (l == 0) out[0] = expf(a) - expf(b) + LAMBDA_INIT_F;
}

// --------------------- 128x128 f16 GEMM:  C = A @ Bt^T ---------------------
__global__ __launch_bounds__(256) void gemm128(const _Float16* __restrict__ A,
                                               const _Float16* __restrict__ Bt,
                                               _Float16* __restrict__ Cf16,
                                               float* __restrict__ Cf32,
                                               int M, int N, int K) {
  __shared__ alignas(16) _Float16 As[128 * 32];
  __shared__ alignas(16) _Float16 Bs[128 * 32];
  const int tid = threadIdx.x;
  const int lane = tid & 63, wid = tid >> 6;
  const int g = lane >> 4, ln = lane & 15;
  const int wm = wid >> 1, wn = wid & 1;
  const int bm = blockIdx.y * 128;
  const int bn = blockIdx.x * 128;

  f32x4 acc[4][4];
#pragma unroll
  for (int i = 0; i < 4; ++i)
#pragma unroll
    for (int j = 0; j < 4; ++j) acc[i][j] = (f32x4){0.f, 0.f, 0.f, 0.f};

  const int r0 = tid >> 2;
  const int c0 = (tid & 3) * 8;

  for (int kt = 0; kt < K; kt += 32) {
    __syncthreads();
#pragma unroll
    for (int l = 0; l < 2; ++l) {
      const _Float16* ga = A + (size_t)(bm + l * 64 + r0) * K + kt + c0;
      const _Float16* gb = Bt + (size_t)(bn + l * 64 + r0) * K + kt + c0;
      gl_lds16(ga, (void*)(As + l * 2048 + wid * 512));
      gl_lds16(gb, (void*)(Bs + l * 2048 + wid * 512));
    }
    __syncthreads();
    f16x8 af[4], bf[4];
#pragma unroll
    for (int i = 0; i < 4; ++i) {
      af[i] = *(const f16x8*)(As + (wm * 64 + i * 16 + ln) * 32 + g * 8);
      bf[i] = *(const f16x8*)(Bs + (wn * 64 + i * 16 + ln) * 32 + g * 8);
    }
#pragma unroll
    for (int i = 0; i < 4; ++i)
#pragma unroll
      for (int j = 0; j < 4; ++j)
        acc[i][j] = __builtin_amdgcn_mfma_f32_16x16x32_f16(af[i], bf[j], acc[i][j], 0, 0, 0);
  }

#pragma unroll
  for (int i = 0; i < 4; ++i) {
#pragma unroll
    for (int j = 0; j < 4; ++j) {
      int grow = bm + wm * 64 + i * 16 + g * 4;
      int gcol = bn + wn * 64 + j * 16 + ln;
#pragma unroll
      for (int r = 0; r < 4; ++r) {
        if (Cf32) Cf32[(size_t)(grow + r) * N + gcol] = acc[i][j][r];
        else      Cf16[(size_t)(grow + r) * N + gcol] = (_Float16)acc[i][j][r];
      }
    }
  }
}

// ------------------- component-split differential attention ----------------
// grid = 1024 blocks (b,h,qtile of 64), 4 waves: wq = wid&1 (q-subtile of 32),
// comp = wid>>1 (softmax component). Per-lane softmax state (col=q layout
// from swapped MFMA). Comp-1 wave ships O2/l2 via LDS; comp-0 finishes.
__global__ __launch_bounds__(256, 4) void diffattn(const _Float16* __restrict__ qb,
                                                   const _Float16* __restrict__ kb,
                                                   const _Float16* __restrict__ vT,
                                                   const float* __restrict__ lam_p,
                                                   const float* __restrict__ subw,
                                                   _Float16* __restrict__ attn16) {
  __shared__ float mrg[2][64][33];   // [wq][lane][normalized O2 (32)]

  const int tid = threadIdx.x;
  const int lane = tid & 63, wid = tid >> 6;
  const int q32 = lane & 31;
  const int hl = lane >> 5;
  const int wq = wid & 1;       // q-subtile within the 64-row tile
  const int comp = wid >> 1;    // softmax component
  const int bid = blockIdx.x;
  const int wg = ((bid & 7) << 7) | (bid >> 3);   // XCD-aware swizzle (1024=8*128)
  const int qt = wg & 31;
  const int h = (wg >> 5) & 15;
  const int b = wg >> 9;
  const int trow = qt * 64 + wq * 32 + q32;

  // Q B-fragments for THIS comp: lane holds Q[q=lane&31][d = 16*kt + 8*hl + i]
  const _Float16* qp = qb + ((size_t)b * 2048 + trow) * 1024 + (2 * h + comp) * 32 + hl * 8;
  f16x8 qf_0 = *(const f16x8*)(qp);
  f16x8 qf_1 = *(const f16x8*)(qp + 16);

  const _Float16* kbase = kb + (size_t)b * 2048 * 1024 + (2 * h + comp) * 32 + hl * 8;
  const _Float16* vbase = vT + ((size_t)(h * 64 + q32)) * 4096 + b * 2048 + hl * 8;

  f32x16 O[2] = {};
  float m = -1e30f, l = 0.f;
  const f32x16 zf = {};

  auto LOADT = [&](f16x8* K2, f16x8* V4, int s0) {
    const _Float16* kp = kbase + (size_t)(s0 + q32) * 1024;
    K2[0] = *(const f16x8*)(kp);
    K2[1] = *(const f16x8*)(kp + 16);
    const _Float16* vp = vbase + s0;
    V4[0] = *(const f16x8*)(vp);
    V4[1] = *(const f16x8*)(vp + 16);
    V4[2] = *(const f16x8*)(vp + 32 * 4096);
    V4[3] = *(const f16x8*)(vp + 32 * 4096 + 16);
  };

  auto PROC = [&](const f16x8* K2, const f16x8* V4) {
    __builtin_amdgcn_s_setprio(1);
    f32x16 st = __builtin_amdgcn_mfma_f32_32x32x16_f16(K2[0], qf_0, zf, 0, 0, 0);
    st = __builtin_amdgcn_mfma_f32_32x32x16_f16(K2[1], qf_1, st, 0, 0, 0);
    __builtin_amdgcn_s_setprio(0);

    float tm = st[0];
#pragma unroll
    for (int i = 1; i < 16; ++i) tm = fmaxf(tm, st[i]);
    tm = fmaxf(tm, __shfl_xor(tm, 32, 64));

    // defer-max (T13): only rescale when tile max exceeds running max + THR
    if (!__all(tm - m <= 11.5f)) {
      float mn = fmaxf(m, tm);
      float c = __builtin_amdgcn_exp2f(m - mn);
      m = mn; l *= c;
#pragma unroll
      for (int i = 0; i < 16; ++i) { O[0][i] *= c; O[1][i] *= c; }
    }

    float p[16];
    float rs = 0.f;
#pragma unroll
    for (int i = 0; i < 16; ++i) {
      p[i] = __builtin_amdgcn_exp2f(st[i] - m);
      rs += p[i];
    }
    l += rs + __shfl_xor(rs, 32, 64);
    f16x2 r[8], xr[8];
#pragma unroll
    for (int k = 0; k < 8; ++k) r[k] = cvtpk(p[2 * k], p[2 * k + 1]);
#pragma unroll
    for (int k = 0; k < 8; ++k) xr[k] = shx32(r[k]);
    union { f16x8 v; f16x2 h2[4]; } u0, u1;
    u0.h2[0] = hl ? xr[2] : r[0];
    u0.h2[1] = hl ? xr[3] : r[1];
    u0.h2[2] = hl ? r[2]  : xr[0];
    u0.h2[3] = hl ? r[3]  : xr[1];
    u1.h2[0] = hl ? xr[6] : r[4];
    u1.h2[1] = hl ? xr[7] : r[5];
    u1.h2[2] = hl ? r[6]  : xr[4];
    u1.h2[3] = hl ? r[7]  : xr[5];

    __builtin_amdgcn_s_setprio(1);
    O[0] = __builtin_amdgcn_mfma_f32_32x32x16_f16(V4[0], u0.v, O[0], 0, 0, 0);
    O[0] = __builtin_amdgcn_mfma_f32_32x32x16_f16(V4[1], u1.v, O[0], 0, 0, 0);
    O[1] = __builtin_amdgcn_mfma_f32_32x32x16_f16(V4[2], u0.v, O[1], 0, 0, 0);
    O[1] = __builtin_amdgcn_mfma_f32_32x32x16_f16(V4[3], u1.v, O[1], 0, 0, 0);
    __builtin_amdgcn_s_setprio(0);
  };

  f16x8 Ka[2], Va[4], Kb[2], Vb[4];
  LOADT(Ka, Va, 0);
  for (int s0 = 0; s0 < 2048; s0 += 64) {
    LOADT(Kb, Vb, s0 + 32);
    PROC(Ka, Va);
    if (s0 + 64 < 2048) LOADT(Ka, Va, s0 + 64);
    PROC(Kb, Vb);
  }

  // ---- comp-1 waves ship normalized O/l; comp-0 waves finish ----
  if (comp == 1) {
    float rl = 1.f / l;
    float* d = &mrg[wq][lane][0];
#pragma unroll
    for (int t = 0; t < 2; ++t)
#pragma unroll
      for (int i = 0; i < 16; ++i) d[t * 16 + i] = O[t][i] * rl;
  }
  __syncthreads();
  if (comp == 1) return;

  const float lam = lam_p[0];
  const float* d = &mrg[wq][lane][0];
  float rl = 1.f / l;
  float x[2][16];
  float ssq = 0.f;
#pragma unroll
  for (int et = 0; et < 2; ++et)
#pragma unroll
    for (int i = 0; i < 16; ++i) {
      float v = O[et][i] * rl - lam * d[et * 16 + i];
      x[et][i] = v;
      ssq += v * v;
    }
  ssq += __shfl_xor(ssq, 32, 64);
  float rms = rsqrtf(ssq * (1.f / 64.f) + 1e-5f) * OUT_SCALE_F;

  _Float16* orow = attn16 + ((size_t)b * 2048 + trow) * 1024 + h * 64;
#pragma unroll
  for (int et = 0; et < 2; ++et)
#pragma unroll
    for (int grp = 0; grp < 4; ++grp) {
      int e0 = et * 32 + grp * 8 + 4 * hl;
      float4 w = *(const float4*)(subw + e0);
      f16x4 o;
      o[0] = (_Float16)(x[et][grp * 4 + 0] * rms * w.x);
      o[1] = (_Float16)(x[et][grp * 4 + 1] * rms * w.y);
      o[2] = (_Float16)(x[et][grp * 4 + 2] * rms * w.z);
      o[3] = (_Float16)(x[et][grp * 4 + 3] * rms * w.w);
      *(f16x4*)(orow + e0) = o;
    }
}

// ---------------------------------------------------------------------------
extern "C" void kernel_launch(void* const* d_in, const int* in_sizes, int n_in,
                              void* d_out, int out_size, void* d_ws, size_t ws_size,
                              hipStream_t stream) {
  const float* query_x = (const float*)d_in[0];
  const float* kv_x    = (const float*)d_in[1];
  const float* Wq      = (const float*)d_in[2];
  const float* Wk      = (const float*)d_in[3];
  const float* Wv      = (const float*)d_in[4];
  const float* Wo      = (const float*)d_in[5];
  const float* lq1     = (const float*)d_in[6];
  const float* lk1     = (const float*)d_in[7];
  const float* lq2     = (const float*)d_in[8];
  const float* lk2     = (const float*)d_in[9];
  const float* subw    = (const float*)d_in[10];
  float* out = (float*)d_out;

  const size_t NX = (size_t)4096 * 1024;
  const size_t NW = (size_t)1024 * 1024;
  _Float16* xq  = (_Float16*)d_ws;
  _Float16* xkv = xq  + NX;
  _Float16* WqT = xkv + NX;
  _Float16* WkT = WqT + NW;
  _Float16* WvT = WkT + NW;
  _Float16* WoT = WvT + NW;
  _Float16* qb  = WoT + NW;
  _Float16* kbf = qb  + NX;
  _Float16* vTb = kbf + NX;   // V^T: [1024 rows = h*64+e][4096 cols = b*2048+s]
  _Float16* a16 = vTb + NX;
  float* lamv   = (float*)(a16 + NX);

  cvt_kernel<<<4096, 256, 0, stream>>>(query_x, xq);
  cvt_kernel<<<4096, 256, 0, stream>>>(kv_x, xkv);

  dim3 tg(16, 16);
  // Wq also folds log2e so attention scores are directly in exp2 domain
  wtrans_kernel<<<tg, 256, 0, stream>>>(Wq, WqT, QK_SCALE_F * LOG2E_F);
  wtrans_kernel<<<tg, 256, 0, stream>>>(Wk, WkT, 1.0f);
  wtrans_kernel<<<tg, 256, 0, stream>>>(Wv, WvT, 1.0f);
  wtrans_kernel<<<tg, 256, 0, stream>>>(Wo, WoT, 1.0f);
  lambda_kernel<<<1, 64, 0, stream>>>(lq1, lk1, lq2, lk2, lamv);

  dim3 gg(8, 32);   // (N/128, M/128) for 4096x1024
  gemm128<<<gg, 256, 0, stream>>>(xq,  WqT, qb,  nullptr, 4096, 1024, 1024);
  gemm128<<<gg, 256, 0, stream>>>(xkv, WkT, kbf, nullptr, 4096, 1024, 1024);
  // V^T directly: C[n][m] = sum_k WvT[n][k]*xkv[m][k] = V[m][n]
  dim3 gv(32, 8);   // (N/128=4096/128, M/128=1024/128)
  gemm128<<<gv, 256, 0, stream>>>(WvT, xkv, vTb, nullptr, 1024, 4096, 1024);

  diffattn<<<1024, 256, 0, stream>>>(qb, kbf, vTb, lamv, subw, a16);

  gemm128<<<gg, 256, 0, stream>>>(a16, WoT, nullptr, out, 4096, 1024, 1024);
}

// Round 6
// 230.771 us; speedup vs baseline: 1.6362x; 1.3500x over previous
//
#include <hip/hip_runtime.h>
#include <stdint.h>

// ---------------------------------------------------------------------------
// CrossMultiheadDiffAttn on MI355X (gfx950)
// B=2, T=S=2048, EMBED=1024, HEADS=16; 2H=32 qk-heads of D=32, 16 v-heads of 64.
//
// Round 6: LDS-staged attention. Comp-split waves (R5) + zero-VGPR K/V
// staging via global_load_lds (double-buffered, T3-minimum schedule) so the
// prefetch survives register allocation. 4-shuffle P-pack, tree reductions.
// ---------------------------------------------------------------------------

#define LAMBDA_INIT_F 0.7836057665316245f
#define OUT_SCALE_F   0.2163942334683755f   /* 1 - LAMBDA_INIT */
#define QK_SCALE_F    0.17677669529663687f  /* 32^-0.5 */
#define LOG2E_F       1.4426950408889634f

typedef _Float16 f16x8 __attribute__((ext_vector_type(8)));
typedef _Float16 f16x4 __attribute__((ext_vector_type(4)));
typedef _Float16 f16x2 __attribute__((ext_vector_type(2)));
typedef __fp16   h16x2 __attribute__((ext_vector_type(2)));
typedef float    f32x4 __attribute__((ext_vector_type(4)));
typedef float    f32x16 __attribute__((ext_vector_type(16)));

__device__ inline void gl_lds16(const void* g, void* l) {
  __builtin_amdgcn_global_load_lds(
      (const __attribute__((address_space(1))) void*)g,
      (__attribute__((address_space(3))) void*)l, 16, 0, 0);
}

__device__ inline f16x2 shx32(f16x2 v) {
  int i = __builtin_bit_cast(int, v);
  i = __shfl_xor(i, 32, 64);
  return __builtin_bit_cast(f16x2, i);
}

__device__ inline f16x2 cvtpk(float a, float b) {
  h16x2 r = __builtin_amdgcn_cvt_pkrtz(a, b);
  return __builtin_bit_cast(f16x2, r);
}

// --------------------------- f32 -> f16 convert ----------------------------
__global__ __launch_bounds__(256) void cvt_kernel(const float* __restrict__ x,
                                                  _Float16* __restrict__ y) {
  int i = (blockIdx.x * 256 + threadIdx.x) * 4;
  float4 v = *(const float4*)(x + i);
  f16x4 o;
  o[0] = (_Float16)v.x; o[1] = (_Float16)v.y;
  o[2] = (_Float16)v.z; o[3] = (_Float16)v.w;
  *(f16x4*)(y + i) = o;
}

// ---------------- W [K,N] f32 -> W^T [N,K] f16 (with scale) ----------------
__global__ __launch_bounds__(256) void wtrans_kernel(const float* __restrict__ W,
                                                     _Float16* __restrict__ Wt,
                                                     float scale) {
  __shared__ _Float16 t[64][65];
  const int tid = threadIdx.x;
  const int nb = blockIdx.x * 64, kb = blockIdx.y * 64;
#pragma unroll
  for (int p = 0; p < 16; ++p) {
    int i = p * 256 + tid;
    int r = i >> 6, c = i & 63;
    t[c][r] = (_Float16)(W[(size_t)(kb + r) * 1024 + nb + c] * scale);
  }
  __syncthreads();
#pragma unroll
  for (int p = 0; p < 16; ++p) {
    int i = p * 256 + tid;
    int r = i >> 6, c = i & 63;
    Wt[(size_t)(nb + r) * 1024 + kb + c] = t[r][c];
  }
}

// ------------------------------ lambda_full --------------------------------
__global__ void lambda_kernel(const float* __restrict__ lq1, const float* __restrict__ lk1,
                              const float* __restrict__ lq2, const float* __restrict__ lk2,
                              float* __restrict__ out) {
  int l = threadIdx.x;
  float a = (l < 32) ? lq1[l] * lk1[l] : 0.f;
  float b = (l < 32) ? lq2[l] * lk2[l] : 0.f;
#pragma unroll
  for (int m = 1; m < 64; m <<= 1) {
    a += __shfl_xor(a, m, 64);
    b += __shfl_xor(b, m, 64);
  }
  if (l == 0) out[0] = expf(a) - expf(b) + LAMBDA_INIT_F;
}

// --------------------- 128x128 f16 GEMM:  C = A @ Bt^T ---------------------
__global__ __launch_bounds__(256) void gemm128(const _Float16* __restrict__ A,
                                               const _Float16* __restrict__ Bt,
                                               _Float16* __restrict__ Cf16,
                                               float* __restrict__ Cf32,
                                               int M, int N, int K) {
  __shared__ alignas(16) _Float16 As[128 * 32];
  __shared__ alignas(16) _Float16 Bs[128 * 32];
  const int tid = threadIdx.x;
  const int lane = tid & 63, wid = tid >> 6;
  const int g = lane >> 4, ln = lane & 15;
  const int wm = wid >> 1, wn = wid & 1;
  const int bm = blockIdx.y * 128;
  const int bn = blockIdx.x * 128;

  f32x4 acc[4][4];
#pragma unroll
  for (int i = 0; i < 4; ++i)
#pragma unroll
    for (int j = 0; j < 4; ++j) acc[i][j] = (f32x4){0.f, 0.f, 0.f, 0.f};

  const int r0 = tid >> 2;
  const int c0 = (tid & 3) * 8;

  for (int kt = 0; kt < K; kt += 32) {
    __syncthreads();
#pragma unroll
    for (int l = 0; l < 2; ++l) {
      const _Float16* ga = A + (size_t)(bm + l * 64 + r0) * K + kt + c0;
      const _Float16* gb = Bt + (size_t)(bn + l * 64 + r0) * K + kt + c0;
      gl_lds16(ga, (void*)(As + l * 2048 + wid * 512));
      gl_lds16(gb, (void*)(Bs + l * 2048 + wid * 512));
    }
    __syncthreads();
    f16x8 af[4], bf[4];
#pragma unroll
    for (int i = 0; i < 4; ++i) {
      af[i] = *(const f16x8*)(As + (wm * 64 + i * 16 + ln) * 32 + g * 8);
      bf[i] = *(const f16x8*)(Bs + (wn * 64 + i * 16 + ln) * 32 + g * 8);
    }
#pragma unroll
    for (int i = 0; i < 4; ++i)
#pragma unroll
      for (int j = 0; j < 4; ++j)
        acc[i][j] = __builtin_amdgcn_mfma_f32_16x16x32_f16(af[i], bf[j], acc[i][j], 0, 0, 0);
  }

#pragma unroll
  for (int i = 0; i < 4; ++i) {
#pragma unroll
    for (int j = 0; j < 4; ++j) {
      int grow = bm + wm * 64 + i * 16 + g * 4;
      int gcol = bn + wn * 64 + j * 16 + ln;
#pragma unroll
      for (int r = 0; r < 4; ++r) {
        if (Cf32) Cf32[(size_t)(grow + r) * N + gcol] = acc[i][j][r];
        else      Cf16[(size_t)(grow + r) * N + gcol] = (_Float16)acc[i][j][r];
      }
    }
  }
}

// ------------------- LDS-staged component-split diff attention --------------
// grid = 1024 blocks (b,h,qtile of 64), 4 waves: wq = wid&1 (q-subtile of 32),
// comp = wid>>1 (softmax component). K(2 comps)+V tile for each 32-s step
// staged to LDS via global_load_lds (8 KB/step, double-buffered).
// Buffer layout (halfs): K1[32][32] @0, K2[32][32] @1024, V[64][32] @2048.
__global__ __launch_bounds__(256, 4) void diffattn(const _Float16* __restrict__ qb,
                                                   const _Float16* __restrict__ kb,
                                                   const _Float16* __restrict__ vT,
                                                   const float* __restrict__ lam_p,
                                                   const float* __restrict__ subw,
                                                   _Float16* __restrict__ attn16) {
  __shared__ alignas(16) _Float16 stg[2][4096];   // 2 x 8 KB staging
  __shared__ float mrg[2][64][33];                // [wq][lane][normalized O2]

  const int tid = threadIdx.x;
  const int lane = tid & 63, wid = tid >> 6;
  const int q32 = lane & 31;
  const int hl = lane >> 5;
  const int wq = wid & 1;       // q-subtile within the 64-row tile
  const int comp = wid >> 1;    // softmax component
  const int bid = blockIdx.x;
  const int wg = ((bid & 7) << 7) | (bid >> 3);   // XCD-aware swizzle (1024=8*128)
  const int qt = wg & 31;
  const int h = (wg >> 5) & 15;
  const int b = wg >> 9;
  const int trow = qt * 64 + wq * 32 + q32;

  // Q B-fragments for THIS comp: lane holds Q[q=lane&31][d = 16*kt + 8*hl + i]
  const _Float16* qp = qb + ((size_t)b * 2048 + trow) * 1024 + (2 * h + comp) * 32 + hl * 8;
  f16x8 qf_0 = *(const f16x8*)(qp);
  f16x8 qf_1 = *(const f16x8*)(qp + 16);

  // staging source (per thread): thread sidx stages 16B
  //   call A: sidx 0..127 -> K1 rows, 128..255 -> K2 rows (4 threads/row)
  //   call B: V rows 0..63 (4 threads/row)
  const int kcomp = tid >> 7;
  const int krow = (tid >> 2) & 31;
  const int vrow = tid >> 2;
  const int c8 = (tid & 3) * 8;
  const _Float16* kg0 = kb + ((size_t)b * 2048 + krow) * 1024 + (2 * h + kcomp) * 32 + c8;
  const _Float16* vg0 = vT + ((size_t)(h * 64 + vrow)) * 4096 + (size_t)b * 2048 + c8;

  f32x16 O[2] = {};
  float m = -1e30f, l = 0.f;
  const f32x16 zf = {};

  auto STAGE = [&](int buf, int s0) {
    gl_lds16(kg0 + (size_t)s0 * 1024, (void*)&stg[buf][wid * 512]);
    gl_lds16(vg0 + s0,                (void*)&stg[buf][2048 + wid * 512]);
  };

  auto PROC = [&](int buf) {
    const _Float16* kp = &stg[buf][comp * 1024 + q32 * 32 + hl * 8];
    f16x8 Kf0 = *(const f16x8*)(kp);
    f16x8 Kf1 = *(const f16x8*)(kp + 16);

    __builtin_amdgcn_s_setprio(1);
    f32x16 st = __builtin_amdgcn_mfma_f32_32x32x16_f16(Kf0, qf_0, zf, 0, 0, 0);
    st = __builtin_amdgcn_mfma_f32_32x32x16_f16(Kf1, qf_1, st, 0, 0, 0);
    __builtin_amdgcn_s_setprio(0);

    // tile max (tree) + cross-half
    float a[8];
#pragma unroll
    for (int i = 0; i < 8; ++i) a[i] = fmaxf(st[2 * i], st[2 * i + 1]);
#pragma unroll
    for (int i = 0; i < 4; ++i) a[i] = fmaxf(a[i], a[i + 4]);
    float tm = fmaxf(fmaxf(a[0], a[1]), fmaxf(a[2], a[3]));
    tm = fmaxf(tm, __shfl_xor(tm, 32, 64));

    // defer-max (T13)
    if (!__all(tm - m <= 11.5f)) {
      float mn = fmaxf(m, tm);
      float c = __builtin_amdgcn_exp2f(m - mn);
      m = mn; l *= c;
#pragma unroll
      for (int i = 0; i < 16; ++i) { O[0][i] *= c; O[1][i] *= c; }
    }

    float p[16];
#pragma unroll
    for (int i = 0; i < 16; ++i) p[i] = __builtin_amdgcn_exp2f(st[i] - m);
    float s8[8];
#pragma unroll
    for (int i = 0; i < 8; ++i) s8[i] = p[2 * i] + p[2 * i + 1];
#pragma unroll
    for (int i = 0; i < 4; ++i) s8[i] += s8[i + 4];
    float rs = (s8[0] + s8[1]) + (s8[2] + s8[3]);
    l += rs + __shfl_xor(rs, 32, 64);

    // pack P -> PV B-frags (4 exchanges: send exactly what partner needs)
    f16x2 r[8];
#pragma unroll
    for (int k = 0; k < 8; ++k) r[k] = cvtpk(p[2 * k], p[2 * k + 1]);
    f16x2 e0 = shx32(hl ? r[0] : r[2]);
    f16x2 e1 = shx32(hl ? r[1] : r[3]);
    f16x2 e2 = shx32(hl ? r[4] : r[6]);
    f16x2 e3 = shx32(hl ? r[5] : r[7]);
    union { f16x8 v; f16x2 h2[4]; } u0, u1;
    u0.h2[0] = hl ? e0 : r[0];
    u0.h2[1] = hl ? e1 : r[1];
    u0.h2[2] = hl ? r[2] : e0;
    u0.h2[3] = hl ? r[3] : e1;
    u1.h2[0] = hl ? e2 : r[4];
    u1.h2[1] = hl ? e3 : r[5];
    u1.h2[2] = hl ? r[6] : e2;
    u1.h2[3] = hl ? r[7] : e3;

    const _Float16* vp = &stg[buf][2048 + q32 * 32 + hl * 8];
    f16x8 Vf0 = *(const f16x8*)(vp);
    f16x8 Vf1 = *(const f16x8*)(vp + 16);
    f16x8 Vf2 = *(const f16x8*)(vp + 1024);
    f16x8 Vf3 = *(const f16x8*)(vp + 1024 + 16);

    __builtin_amdgcn_s_setprio(1);
    O[0] = __builtin_amdgcn_mfma_f32_32x32x16_f16(Vf0, u0.v, O[0], 0, 0, 0);
    O[0] = __builtin_amdgcn_mfma_f32_32x32x16_f16(Vf1, u1.v, O[0], 0, 0, 0);
    O[1] = __builtin_amdgcn_mfma_f32_32x32x16_f16(Vf2, u0.v, O[1], 0, 0, 0);
    O[1] = __builtin_amdgcn_mfma_f32_32x32x16_f16(Vf3, u1.v, O[1], 0, 0, 0);
    __builtin_amdgcn_s_setprio(0);
  };

  STAGE(0, 0);
  __syncthreads();
  int buf = 0;
  for (int s0 = 0; s0 < 2048; s0 += 32) {
    if (s0 + 32 < 2048) STAGE(buf ^ 1, s0 + 32);
    PROC(buf);
    __syncthreads();   // drains the just-issued stage (had full PROC to land)
    buf ^= 1;
  }

  // ---- comp-1 waves ship normalized O; comp-0 waves finish ----
  if (comp == 1) {
    float rl = 1.f / l;
    float* d = &mrg[wq][lane][0];
#pragma unroll
    for (int t = 0; t < 2; ++t)
#pragma unroll
      for (int i = 0; i < 16; ++i) d[t * 16 + i] = O[t][i] * rl;
  }
  __syncthreads();
  if (comp == 1) return;

  const float lam = lam_p[0];
  const float* d = &mrg[wq][lane][0];
  float rl = 1.f / l;
  float x[2][16];
  float ssq = 0.f;
#pragma unroll
  for (int et = 0; et < 2; ++et)
#pragma unroll
    for (int i = 0; i < 16; ++i) {
      float v = O[et][i] * rl - lam * d[et * 16 + i];
      x[et][i] = v;
      ssq += v * v;
    }
  ssq += __shfl_xor(ssq, 32, 64);
  float rms = rsqrtf(ssq * (1.f / 64.f) + 1e-5f) * OUT_SCALE_F;

  _Float16* orow = attn16 + ((size_t)b * 2048 + trow) * 1024 + h * 64;
#pragma unroll
  for (int et = 0; et < 2; ++et)
#pragma unroll
    for (int grp = 0; grp < 4; ++grp) {
      int e0 = et * 32 + grp * 8 + 4 * hl;
      float4 w = *(const float4*)(subw + e0);
      f16x4 o;
      o[0] = (_Float16)(x[et][grp * 4 + 0] * rms * w.x);
      o[1] = (_Float16)(x[et][grp * 4 + 1] * rms * w.y);
      o[2] = (_Float16)(x[et][grp * 4 + 2] * rms * w.z);
      o[3] = (_Float16)(x[et][grp * 4 + 3] * rms * w.w);
      *(f16x4*)(orow + e0) = o;
    }
}

// ---------------------------------------------------------------------------
extern "C" void kernel_launch(void* const* d_in, const int* in_sizes, int n_in,
                              void* d_out, int out_size, void* d_ws, size_t ws_size,
                              hipStream_t stream) {
  const float* query_x = (const float*)d_in[0];
  const float* kv_x    = (const float*)d_in[1];
  const float* Wq      = (const float*)d_in[2];
  const float* Wk      = (const float*)d_in[3];
  const float* Wv      = (const float*)d_in[4];
  const float* Wo      = (const float*)d_in[5];
  const float* lq1     = (const float*)d_in[6];
  const float* lk1     = (const float*)d_in[7];
  const float* lq2     = (const float*)d_in[8];
  const float* lk2     = (const float*)d_in[9];
  const float* subw    = (const float*)d_in[10];
  float* out = (float*)d_out;

  const size_t NX = (size_t)4096 * 1024;
  const size_t NW = (size_t)1024 * 1024;
  _Float16* xq  = (_Float16*)d_ws;
  _Float16* xkv = xq  + NX;
  _Float16* WqT = xkv + NX;
  _Float16* WkT = WqT + NW;
  _Float16* WvT = WkT + NW;
  _Float16* WoT = WvT + NW;
  _Float16* qb  = WoT + NW;
  _Float16* kbf = qb  + NX;
  _Float16* vTb = kbf + NX;   // V^T: [1024 rows = h*64+e][4096 cols = b*2048+s]
  _Float16* a16 = vTb + NX;
  float* lamv   = (float*)(a16 + NX);

  cvt_kernel<<<4096, 256, 0, stream>>>(query_x, xq);
  cvt_kernel<<<4096, 256, 0, stream>>>(kv_x, xkv);

  dim3 tg(16, 16);
  // Wq also folds log2e so attention scores are directly in exp2 domain
  wtrans_kernel<<<tg, 256, 0, stream>>>(Wq, WqT, QK_SCALE_F * LOG2E_F);
  wtrans_kernel<<<tg, 256, 0, stream>>>(Wk, WkT, 1.0f);
  wtrans_kernel<<<tg, 256, 0, stream>>>(Wv, WvT, 1.0f);
  wtrans_kernel<<<tg, 256, 0, stream>>>(Wo, WoT, 1.0f);
  lambda_kernel<<<1, 64, 0, stream>>>(lq1, lk1, lq2, lk2, lamv);

  dim3 gg(8, 32);   // (N/128, M/128) for 4096x1024
  gemm128<<<gg, 256, 0, stream>>>(xq,  WqT, qb,  nullptr, 4096, 1024, 1024);
  gemm128<<<gg, 256, 0, stream>>>(xkv, WkT, kbf, nullptr, 4096, 1024, 1024);
  // V^T directly: C[n][m] = sum_k WvT[n][k]*xkv[m][k] = V[m][n]
  dim3 gv(32, 8);   // (N/128=4096/128, M/128=1024/128)
  gemm128<<<gv, 256, 0, stream>>>(WvT, xkv, vTb, nullptr, 1024, 4096, 1024);

  diffattn<<<1024, 256, 0, stream>>>(qb, kbf, vTb, lamv, subw, a16);

  gemm128<<<gg, 256, 0, stream>>>(a16, WoT, nullptr, out, 4096, 1024, 1024);
}

// Round 7
// 195.736 us; speedup vs baseline: 1.9290x; 1.1790x over previous
//
#include <hip/hip_runtime.h>
#include <stdint.h>

// ---------------------------------------------------------------------------
// CrossMultiheadDiffAttn on MI355X (gfx950)
// B=2, T=S=2048, EMBED=1024, HEADS=16; 2H=32 qk-heads of D=32, 16 v-heads of 64.
//
// Round 7: bank-conflict-free LDS layouts everywhere.
//  - chunk-XOR swizzle (16B granularity) realized via pre-permuted global
//    sources feeding linear global_load_lds destinations (rule #21).
//  - diffattn: 64-s staging steps (half the barriers), 2 sub-PROCs/buffer,
//    mrg aliased onto staging LDS (32 KB -> 4 blocks/CU).
//  - gemm128: 128x64 tiles -> 512-block grids (2 blocks/CU), prefetch,
//    XCD swizzle, conflict-free A/B reads.
// ---------------------------------------------------------------------------

#define LAMBDA_INIT_F 0.7836057665316245f
#define OUT_SCALE_F   0.2163942334683755f   /* 1 - LAMBDA_INIT */
#define QK_SCALE_F    0.17677669529663687f  /* 32^-0.5 */
#define LOG2E_F       1.4426950408889634f

typedef _Float16 f16x8 __attribute__((ext_vector_type(8)));
typedef _Float16 f16x4 __attribute__((ext_vector_type(4)));
typedef _Float16 f16x2 __attribute__((ext_vector_type(2)));
typedef __fp16   h16x2 __attribute__((ext_vector_type(2)));
typedef float    f32x4 __attribute__((ext_vector_type(4)));
typedef float    f32x16 __attribute__((ext_vector_type(16)));

__device__ inline void gl_lds16(const void* g, void* l) {
  __builtin_amdgcn_global_load_lds(
      (const __attribute__((address_space(1))) void*)g,
      (__attribute__((address_space(3))) void*)l, 16, 0, 0);
}

__device__ inline f16x2 shx32(f16x2 v) {
  int i = __builtin_bit_cast(int, v);
  i = __shfl_xor(i, 32, 64);
  return __builtin_bit_cast(f16x2, i);
}

__device__ inline f16x2 cvtpk(float a, float b) {
  h16x2 r = __builtin_amdgcn_cvt_pkrtz(a, b);
  return __builtin_bit_cast(f16x2, r);
}

// --------------------------- f32 -> f16 convert ----------------------------
__global__ __launch_bounds__(256) void cvt_kernel(const float* __restrict__ x,
                                                  _Float16* __restrict__ y) {
  int i = (blockIdx.x * 256 + threadIdx.x) * 4;
  float4 v = *(const float4*)(x + i);
  f16x4 o;
  o[0] = (_Float16)v.x; o[1] = (_Float16)v.y;
  o[2] = (_Float16)v.z; o[3] = (_Float16)v.w;
  *(f16x4*)(y + i) = o;
}

// ---------------- W [K,N] f32 -> W^T [N,K] f16 (with scale) ----------------
__global__ __launch_bounds__(256) void wtrans_kernel(const float* __restrict__ W,
                                                     _Float16* __restrict__ Wt,
                                                     float scale) {
  __shared__ _Float16 t[64][65];
  const int tid = threadIdx.x;
  const int nb = blockIdx.x * 64, kb = blockIdx.y * 64;
#pragma unroll
  for (int p = 0; p < 16; ++p) {
    int i = p * 256 + tid;
    int r = i >> 6, c = i & 63;
    t[c][r] = (_Float16)(W[(size_t)(kb + r) * 1024 + nb + c] * scale);
  }
  __syncthreads();
#pragma unroll
  for (int p = 0; p < 16; ++p) {
    int i = p * 256 + tid;
    int r = i >> 6, c = i & 63;
    Wt[(size_t)(nb + r) * 1024 + kb + c] = t[r][c];
  }
}

// ------------------------------ lambda_full --------------------------------
__global__ void lambda_kernel(const float* __restrict__ lq1, const float* __restrict__ lk1,
                              const float* __restrict__ lq2, const float* __restrict__ lk2,
                              float* __restrict__ out) {
  int l = threadIdx.x;
  float a = (l < 32) ? lq1[l] * lk1[l] : 0.f;
  float b = (l < 32) ? lq2[l] * lk2[l] : 0.f;
#pragma unroll
  for (int m = 1; m < 64; m <<= 1) {
    a += __shfl_xor(a, m, 64);
    b += __shfl_xor(b, m, 64);
  }
  if (l == 0) out[0] = expf(a) - expf(b) + LAMBDA_INIT_F;
}

// --------------------- 128x64 f16 GEMM:  C = A @ Bt^T ----------------------
// A [M,K] f16 row-major, Bt [N,K] f16 row-major. grid.x = N/64, grid.y = M/128.
// 4 waves; wave wid owns rows [wid*32, wid*32+32) x all 64 cols.
// LDS tiles chunk-XOR swizzled: chunk (r,c) at idx r*4 + ((c + ((r>>1)&3))&3).
__global__ __launch_bounds__(256) void gemm128(const _Float16* __restrict__ A,
                                               const _Float16* __restrict__ Bt,
                                               _Float16* __restrict__ Cf16,
                                               float* __restrict__ Cf32,
                                               int M, int N, int K) {
  __shared__ alignas(16) _Float16 As[2][4096];
  __shared__ alignas(16) _Float16 Bs[2][2048];
  const int tid = threadIdx.x;
  const int lane = tid & 63, wid = tid >> 6;
  const int g = lane >> 4, ln = lane & 15;

  // XCD-aware bijective swizzle (all our grids are multiples of 8)
  const int nwg = gridDim.x * gridDim.y;
  const int bid0 = blockIdx.y * gridDim.x + blockIdx.x;
  const int bid = (bid0 & 7) * (nwg >> 3) + (bid0 >> 3);
  const int nbn = N >> 6;
  const int bn = (bid % nbn) * 64;
  const int bm = (bid / nbn) * 128;

  f32x4 acc[2][4];
#pragma unroll
  for (int i = 0; i < 2; ++i)
#pragma unroll
    for (int j = 0; j < 4; ++j) acc[i][j] = (f32x4){0.f, 0.f, 0.f, 0.f};

  // staging: thread stages chunk idx; idx -> (r = idx>>2, c' = idx&3),
  // global chunk c = (c' - ((r>>1)&3)) & 3  (4 consecutive lanes = one 64B row)
  const int sr = tid >> 2;  // row within 64-row half
  // read offsets (f16 elems), loop-invariant
  int aoff[2], boff[4];
#pragma unroll
  for (int i = 0; i < 2; ++i) {
    int r = wid * 32 + i * 16 + ln;
    aoff[i] = r * 32 + (((g + ((r >> 1) & 3)) & 3) << 3);
  }
#pragma unroll
  for (int j = 0; j < 4; ++j) {
    int r = j * 16 + ln;
    boff[j] = r * 32 + (((g + ((r >> 1) & 3)) & 3) << 3);
  }

  auto STAGE = [&](int buf, int kt) {
#pragma unroll
    for (int l = 0; l < 2; ++l) {
      int r = l * 64 + sr;
      int c = ((tid & 3) - ((r >> 1) & 3)) & 3;
      gl_lds16(A + (size_t)(bm + r) * K + kt + c * 8,
               (void*)&As[buf][l * 2048 + wid * 512]);
    }
    {
      int r = sr;
      int c = ((tid & 3) - ((r >> 1) & 3)) & 3;
      gl_lds16(Bt + (size_t)(bn + r) * K + kt + c * 8,
               (void*)&Bs[buf][wid * 512]);
    }
  };

  STAGE(0, 0);
  __syncthreads();
  int buf = 0;
  for (int kt = 0; kt < K; kt += 32) {
    if (kt + 32 < K) STAGE(buf ^ 1, kt + 32);
    f16x8 af[2], bf[4];
#pragma unroll
    for (int i = 0; i < 2; ++i) af[i] = *(const f16x8*)(&As[buf][aoff[i]]);
#pragma unroll
    for (int j = 0; j < 4; ++j) bf[j] = *(const f16x8*)(&Bs[buf][boff[j]]);
#pragma unroll
    for (int i = 0; i < 2; ++i)
#pragma unroll
      for (int j = 0; j < 4; ++j)
        acc[i][j] = __builtin_amdgcn_mfma_f32_16x16x32_f16(af[i], bf[j], acc[i][j], 0, 0, 0);
    __syncthreads();
    buf ^= 1;
  }

#pragma unroll
  for (int i = 0; i < 2; ++i) {
#pragma unroll
    for (int j = 0; j < 4; ++j) {
      int grow = bm + wid * 32 + i * 16 + g * 4;
      int gcol = bn + j * 16 + ln;
#pragma unroll
      for (int r = 0; r < 4; ++r) {
        if (Cf32) Cf32[(size_t)(grow + r) * N + gcol] = acc[i][j][r];
        else      Cf16[(size_t)(grow + r) * N + gcol] = (_Float16)acc[i][j][r];
      }
    }
  }
}

// ------------- LDS-staged component-split diff attention (swizzled) ---------
// grid = 1024 blocks (b,h,qtile of 64), 4 waves: wq = wid&1, comp = wid>>1.
// Per 64-s step one buffer: K1[64x32] @0, K2 @2048, V[64e x 64s] @4096 (elems).
// K chunk (r,c): idx r*4 + ((c + ((r>>1)&3))&3); V chunk (e,cs): e*8 + ((cs+e)&7... via (e&7)).
__global__ __launch_bounds__(256, 4) void diffattn(const _Float16* __restrict__ qb,
                                                   const _Float16* __restrict__ kb,
                                                   const _Float16* __restrict__ vT,
                                                   const float* __restrict__ lam_p,
                                                   const float* __restrict__ subw,
                                                   _Float16* __restrict__ attn16) {
  __shared__ alignas(16) _Float16 stg[2][8192];   // 2 x 16 KB
  float* mrg = (float*)&stg[0][0];                // aliased after main loop

  const int tid = threadIdx.x;
  const int lane = tid & 63, wid = tid >> 6;
  const int q32 = lane & 31;
  const int hl = lane >> 5;
  const int wq = wid & 1;       // q-subtile within the 64-row tile
  const int comp = wid >> 1;    // softmax component
  const int bid = blockIdx.x;
  const int wg = ((bid & 7) << 7) | (bid >> 3);   // XCD swizzle (1024=8*128)
  const int qt = wg & 31;
  const int h = (wg >> 5) & 15;
  const int b = wg >> 9;
  const int trow = qt * 64 + wq * 32 + q32;

  // Q B-fragments for THIS comp: lane holds Q[q=lane&31][d = 16*kt + 8*hl + i]
  const _Float16* qp = qb + ((size_t)b * 2048 + trow) * 1024 + (2 * h + comp) * 32 + hl * 8;
  f16x8 qf_0 = *(const f16x8*)(qp);
  f16x8 qf_1 = *(const f16x8*)(qp + 16);

  // ---- staging sources (pre-permuted for swizzled LDS layout) ----
  // K: wave wid stages rows [wid*16, wid*16+16), 4 lanes/row
  const int kr = wid * 16 + (lane >> 2);
  const int kc = ((lane & 3) - ((kr >> 1) & 3)) & 3;
  const _Float16* kg = kb + ((size_t)b * 2048 + kr) * 1024 + 2 * h * 32 + kc * 8;
  // V: slot s = wid (+4): e = s*8 + (lane>>3), cs = ((lane&7) - (lane>>3)) & 7
  const int ve = lane >> 3;
  const int vcs = ((lane & 7) - ve) & 7;
  const _Float16* vg = vT + ((size_t)(h * 64 + wid * 8 + ve)) * 4096 + (size_t)b * 2048 + vcs * 8;

  // ---- read-offset precompute (f16 elems), loop-invariant ----
  const int kswz = (q32 >> 1) & 3;
  const int ko0 = ((hl + kswz) & 3) << 3;
  const int ko1 = ((hl + 2 + kswz) & 3) << 3;
  const int e7 = q32 & 7;
  const int vo00 = (((hl) + e7) & 7) << 3;         // sub0, k-half0
  const int vo01 = (((hl + 2) + e7) & 7) << 3;     // sub0, k-half1
  const int vo10 = (((hl + 4) + e7) & 7) << 3;     // sub1, k-half0
  const int vo11 = (((hl + 6) + e7) & 7) << 3;     // sub1, k-half1

  f32x16 O[2] = {};
  float m = -1e30f, l = 0.f;
  const f32x16 zf = {};

  auto STAGE = [&](int buf, int s0) {
    gl_lds16(kg + (size_t)s0 * 1024,        (void*)&stg[buf][wid * 512]);          // K1
    gl_lds16(kg + (size_t)s0 * 1024 + 32,   (void*)&stg[buf][2048 + wid * 512]);   // K2
    gl_lds16(vg + s0,                        (void*)&stg[buf][4096 + wid * 512]);  // V e-lo
    gl_lds16(vg + (size_t)32 * 4096 + s0,    (void*)&stg[buf][4096 + (4 + wid) * 512]); // V e-hi
  };

  auto PROC = [&](int buf, int sub) {
    const _Float16* sb = &stg[buf][0];
    const int kbase = comp * 2048 + sub * 1024 + q32 * 32;
    f16x8 Kf0 = *(const f16x8*)(sb + kbase + ko0);
    f16x8 Kf1 = *(const f16x8*)(sb + kbase + ko1);

    __builtin_amdgcn_s_setprio(1);
    f32x16 st = __builtin_amdgcn_mfma_f32_32x32x16_f16(Kf0, qf_0, zf, 0, 0, 0);
    st = __builtin_amdgcn_mfma_f32_32x32x16_f16(Kf1, qf_1, st, 0, 0, 0);
    __builtin_amdgcn_s_setprio(0);

    // tile max (tree) + cross-half
    float a[8];
#pragma unroll
    for (int i = 0; i < 8; ++i) a[i] = fmaxf(st[2 * i], st[2 * i + 1]);
#pragma unroll
    for (int i = 0; i < 4; ++i) a[i] = fmaxf(a[i], a[i + 4]);
    float tm = fmaxf(fmaxf(a[0], a[1]), fmaxf(a[2], a[3]));
    tm = fmaxf(tm, __shfl_xor(tm, 32, 64));

    // defer-max (T13)
    if (!__all(tm - m <= 11.5f)) {
      float mn = fmaxf(m, tm);
      float c = __builtin_amdgcn_exp2f(m - mn);
      m = mn; l *= c;
#pragma unroll
      for (int i = 0; i < 16; ++i) { O[0][i] *= c; O[1][i] *= c; }
    }

    float p[16];
#pragma unroll
    for (int i = 0; i < 16; ++i) p[i] = __builtin_amdgcn_exp2f(st[i] - m);
    float s8[8];
#pragma unroll
    for (int i = 0; i < 8; ++i) s8[i] = p[2 * i] + p[2 * i + 1];
#pragma unroll
    for (int i = 0; i < 4; ++i) s8[i] += s8[i + 4];
    float rs = (s8[0] + s8[1]) + (s8[2] + s8[3]);
    l += rs + __shfl_xor(rs, 32, 64);

    // pack P -> PV B-frags (4 exchanges)
    f16x2 r[8];
#pragma unroll
    for (int k = 0; k < 8; ++k) r[k] = cvtpk(p[2 * k], p[2 * k + 1]);
    f16x2 e0 = shx32(hl ? r[0] : r[2]);
    f16x2 e1 = shx32(hl ? r[1] : r[3]);
    f16x2 e2 = shx32(hl ? r[4] : r[6]);
    f16x2 e3 = shx32(hl ? r[5] : r[7]);
    union { f16x8 v; f16x2 h2[4]; } u0, u1;
    u0.h2[0] = hl ? e0 : r[0];
    u0.h2[1] = hl ? e1 : r[1];
    u0.h2[2] = hl ? r[2] : e0;
    u0.h2[3] = hl ? r[3] : e1;
    u1.h2[0] = hl ? e2 : r[4];
    u1.h2[1] = hl ? e3 : r[5];
    u1.h2[2] = hl ? r[6] : e2;
    u1.h2[3] = hl ? r[7] : e3;

    const int vbase = 4096 + q32 * 64;
    f16x8 Vf0 = *(const f16x8*)(sb + vbase + (sub ? vo10 : vo00));
    f16x8 Vf1 = *(const f16x8*)(sb + vbase + (sub ? vo11 : vo01));
    f16x8 Vf2 = *(const f16x8*)(sb + vbase + 2048 + (sub ? vo10 : vo00));
    f16x8 Vf3 = *(const f16x8*)(sb + vbase + 2048 + (sub ? vo11 : vo01));

    __builtin_amdgcn_s_setprio(1);
    O[0] = __builtin_amdgcn_mfma_f32_32x32x16_f16(Vf0, u0.v, O[0], 0, 0, 0);
    O[0] = __builtin_amdgcn_mfma_f32_32x32x16_f16(Vf1, u1.v, O[0], 0, 0, 0);
    O[1] = __builtin_amdgcn_mfma_f32_32x32x16_f16(Vf2, u0.v, O[1], 0, 0, 0);
    O[1] = __builtin_amdgcn_mfma_f32_32x32x16_f16(Vf3, u1.v, O[1], 0, 0, 0);
    __builtin_amdgcn_s_setprio(0);
  };

  STAGE(0, 0);
  __syncthreads();
  int buf = 0;
  for (int s0 = 0; s0 < 2048; s0 += 64) {
    if (s0 + 64 < 2048) STAGE(buf ^ 1, s0 + 64);
    PROC(buf, 0);
    PROC(buf, 1);
    __syncthreads();
    buf ^= 1;
  }

  // ---- comp-1 waves ship normalized O via (aliased) LDS; comp-0 finish ----
  if (comp == 1) {
    float rl = 1.f / l;
    float* d = mrg + (wq * 64 + lane) * 33;
#pragma unroll
    for (int t = 0; t < 2; ++t)
#pragma unroll
      for (int i = 0; i < 16; ++i) d[t * 16 + i] = O[t][i] * rl;
  }
  __syncthreads();
  if (comp == 1) return;

  const float lam = lam_p[0];
  const float* d = mrg + (wq * 64 + lane) * 33;
  float rl = 1.f / l;
  float x[2][16];
  float ssq = 0.f;
#pragma unroll
  for (int et = 0; et < 2; ++et)
#pragma unroll
    for (int i = 0; i < 16; ++i) {
      float v = O[et][i] * rl - lam * d[et * 16 + i];
      x[et][i] = v;
      ssq += v * v;
    }
  ssq += __shfl_xor(ssq, 32, 64);
  float rms = rsqrtf(ssq * (1.f / 64.f) + 1e-5f) * OUT_SCALE_F;

  _Float16* orow = attn16 + ((size_t)b * 2048 + trow) * 1024 + h * 64;
#pragma unroll
  for (int et = 0; et < 2; ++et)
#pragma unroll
    for (int grp = 0; grp < 4; ++grp) {
      int e0 = et * 32 + grp * 8 + 4 * hl;
      float4 w = *(const float4*)(subw + e0);
      f16x4 o;
      o[0] = (_Float16)(x[et][grp * 4 + 0] * rms * w.x);
      o[1] = (_Float16)(x[et][grp * 4 + 1] * rms * w.y);
      o[2] = (_Float16)(x[et][grp * 4 + 2] * rms * w.z);
      o[3] = (_Float16)(x[et][grp * 4 + 3] * rms * w.w);
      *(f16x4*)(orow + e0) = o;
    }
}

// ---------------------------------------------------------------------------
extern "C" void kernel_launch(void* const* d_in, const int* in_sizes, int n_in,
                              void* d_out, int out_size, void* d_ws, size_t ws_size,
                              hipStream_t stream) {
  const float* query_x = (const float*)d_in[0];
  const float* kv_x    = (const float*)d_in[1];
  const float* Wq      = (const float*)d_in[2];
  const float* Wk      = (const float*)d_in[3];
  const float* Wv      = (const float*)d_in[4];
  const float* Wo      = (const float*)d_in[5];
  const float* lq1     = (const float*)d_in[6];
  const float* lk1     = (const float*)d_in[7];
  const float* lq2     = (const float*)d_in[8];
  const float* lk2     = (const float*)d_in[9];
  const float* subw    = (const float*)d_in[10];
  float* out = (float*)d_out;

  const size_t NX = (size_t)4096 * 1024;
  const size_t NW = (size_t)1024 * 1024;
  _Float16* xq  = (_Float16*)d_ws;
  _Float16* xkv = xq  + NX;
  _Float16* WqT = xkv + NX;
  _Float16* WkT = WqT + NW;
  _Float16* WvT = WkT + NW;
  _Float16* WoT = WvT + NW;
  _Float16* qb  = WoT + NW;
  _Float16* kbf = qb  + NX;
  _Float16* vTb = kbf + NX;   // V^T: [1024 rows = h*64+e][4096 cols = b*2048+s]
  _Float16* a16 = vTb + NX;
  float* lamv   = (float*)(a16 + NX);

  cvt_kernel<<<4096, 256, 0, stream>>>(query_x, xq);
  cvt_kernel<<<4096, 256, 0, stream>>>(kv_x, xkv);

  dim3 tg(16, 16);
  // Wq also folds log2e so attention scores are directly in exp2 domain
  wtrans_kernel<<<tg, 256, 0, stream>>>(Wq, WqT, QK_SCALE_F * LOG2E_F);
  wtrans_kernel<<<tg, 256, 0, stream>>>(Wk, WkT, 1.0f);
  wtrans_kernel<<<tg, 256, 0, stream>>>(Wv, WvT, 1.0f);
  wtrans_kernel<<<tg, 256, 0, stream>>>(Wo, WoT, 1.0f);
  lambda_kernel<<<1, 64, 0, stream>>>(lq1, lk1, lq2, lk2, lamv);

  // grids: (N/64, M/128); all multiples of 8 (XCD swizzle bijective)
  dim3 gq(16, 32);   // 4096x1024
  gemm128<<<gq, 256, 0, stream>>>(xq,  WqT, qb,  nullptr, 4096, 1024, 1024);
  gemm128<<<gq, 256, 0, stream>>>(xkv, WkT, kbf, nullptr, 4096, 1024, 1024);
  // V^T directly: C[n][m] = sum_k WvT[n][k]*xkv[m][k] = V[m][n]
  dim3 gv(64, 8);    // 1024x4096
  gemm128<<<gv, 256, 0, stream>>>(WvT, xkv, vTb, nullptr, 1024, 4096, 1024);

  diffattn<<<1024, 256, 0, stream>>>(qb, kbf, vTb, lamv, subw, a16);

  gemm128<<<gq, 256, 0, stream>>>(a16, WoT, nullptr, out, 4096, 1024, 1024);
}